// Round 5
// baseline (303.791 us; speedup 1.0000x reference)
//
#include <hip/hip_runtime.h>
#include <stdint.h>

#define N_TOK 64
#define K_DIM 4096
#define N_OUT 11008
#define LUT_N 256

typedef __attribute__((ext_vector_type(4))) float  floatx4;
typedef __attribute__((ext_vector_type(8))) __bf16 bf16x8;

__device__ __forceinline__ unsigned bf16_rne(float f) {
  unsigned u = __builtin_bit_cast(unsigned, f);
  return (u + 0x7fffu + ((u >> 16) & 1u)) >> 16;  // round-nearest-even to bf16
}

// ---- pass 1a: pack x (fp32 [64][4096]) into A-fragment-ordered bf16 ----
// chunk c = kstep*4 + tt, kstep in [0,128); lane (q=lane>>4, m15=lane&15)
// holds 8 bf16: x[(tt*16+m15)*4096 + kstep*32 + q*8 + j]
__global__ __launch_bounds__(256) void xpack_kernel(const float* __restrict__ x,
                                                    uint32_t* __restrict__ xp) {
  const int t = blockIdx.x * 256 + threadIdx.x;  // [0, 32768)
  const int lane = t & 63, c = t >> 6;
  const int m15 = lane & 15, q = lane >> 4;
  const int tt = c & 3, kstep = c >> 2;
  const int src = (tt * 16 + m15) * K_DIM + kstep * 32 + q * 8;
  float4 a = *(const float4*)(x + src);
  float4 b = *(const float4*)(x + src + 4);
  uint4 o;
  o.x = bf16_rne(a.x) | (bf16_rne(a.y) << 16);
  o.y = bf16_rne(a.z) | (bf16_rne(a.w) << 16);
  o.z = bf16_rne(b.x) | (bf16_rne(b.y) << 16);
  o.w = bf16_rne(b.z) | (bf16_rne(b.w) << 16);
  *(uint4*)(xp + (size_t)t * 4) = o;
}

// ---- pass 1b: streaming dequant, idx -> bf16 W in MFMA-B-fragment tile order
// Thread t handles row o = t>>9, k-chunk kc = t&511 (8 consecutive k).
// Output tile (to=o>>4, tk=kc>>2) is 1 KB; this thread's 8 bf16 land at
// 16-B unit m*4+q (m=o&15, q=kc&3)  =>  B-frag element j = W[k=q*8+j][n=m].
// Reads: 2 KB contiguous per wave. Writes: full 64-B lines (4 lanes/line).
__global__ __launch_bounds__(256) void dequant_kernel(const int* __restrict__ gi,
                                                      const float* __restrict__ lut,
                                                      uint4* __restrict__ wt) {
  __shared__ uint32_t lut_lds[LUT_N * 16];  // 16 bank-strided copies, bf16 in low16
  {
    unsigned hb = bf16_rne(lut[threadIdx.x]);
#pragma unroll
    for (int c = 0; c < 16; ++c) lut_lds[threadIdx.x * 16 + c] = hb;
  }
  __syncthreads();

  const int slot = threadIdx.x & 15;
  const size_t t = (size_t)blockIdx.x * 256 + threadIdx.x;  // [0, 5636096)
  const int o = (int)(t >> 9);
  const int kc = (int)(t & 511);

  const int4* p = (const int4*)(gi + ((size_t)o << 12) + (kc << 3));
  const int4 a = p[0], b = p[1];

  unsigned g0 = lut_lds[a.x * 16 + slot];
  unsigned g1 = lut_lds[a.y * 16 + slot];
  unsigned g2 = lut_lds[a.z * 16 + slot];
  unsigned g3 = lut_lds[a.w * 16 + slot];
  unsigned g4 = lut_lds[b.x * 16 + slot];
  unsigned g5 = lut_lds[b.y * 16 + slot];
  unsigned g6 = lut_lds[b.z * 16 + slot];
  unsigned g7 = lut_lds[b.w * 16 + slot];
  uint4 u;
  u.x = __builtin_amdgcn_perm(g1, g0, 0x05040100u);  // [bf16(k0)|bf16(k1)<<16]
  u.y = __builtin_amdgcn_perm(g3, g2, 0x05040100u);
  u.z = __builtin_amdgcn_perm(g5, g4, 0x05040100u);
  u.w = __builtin_amdgcn_perm(g7, g6, 0x05040100u);

  const int to = o >> 4, m = o & 15, tk = kc >> 2, q = kc & 3;
  wt[((size_t)to * 128 + tk) * 64 + m * 4 + q] = u;
}

// ---- pass 2: dense bf16 GEMM, fragment-direct loads, no LDS in K-loop ----
// block: 16 output features (= one tile-row of wt), 4 waves; wave w owns
// kstep in [w*32, w*32+32). Both streams register-pipelined depth 4.
// MFMA 16x16x32 bf16: A[m=lane&15][k=q*8+j], B[k=q*8+j][n=lane&15];
// C/D: row(token)=q*4+reg, col(feature)=lane&15.
__global__ __launch_bounds__(256, 3) void gemm_kernel(
    const uint4* __restrict__ wt, const uint32_t* __restrict__ xp,
    const float* __restrict__ scale, float* __restrict__ out) {
  __shared__ floatx4 red[4][4][64];  // 16 KB cross-wave reduction buffer

  const int tid = threadIdx.x;
  const int w = tid >> 6, lane = tid & 63;
  const int m15 = lane & 15, q = lane >> 4;

  // B: tile (blk, kstep), this lane's unit m15*4+q
  const uint4* bp = wt + (size_t)blockIdx.x * 128 * 64 + m15 * 4 + q;
  // A: chunk kstep*4+tt, + lane
  const uint4* ap = (const uint4*)xp + lane;

  floatx4 acc[4];
#pragma unroll
  for (int tt = 0; tt < 4; ++tt) acc[tt] = (floatx4){0.f, 0.f, 0.f, 0.f};

  uint4 bb[4];     // B pipeline, depth 4
  uint4 ab[4][4];  // A pipeline, depth 4 x 4 token-tiles
#pragma unroll
  for (int p = 0; p < 4; ++p) {
    bb[p] = bp[(size_t)(w * 32 + p) * 64];
#pragma unroll
    for (int tt = 0; tt < 4; ++tt)
      ab[p][tt] = ap[(size_t)((w * 32 + p) * 4 + tt) * 64];
  }

#pragma unroll 4
  for (int st = 0; st < 32; ++st) {
    const int p = st & 3;
    const uint4 bv = bb[p];
    uint4 a0 = ab[p][0], a1 = ab[p][1], a2 = ab[p][2], a3 = ab[p][3];
    if (st < 28) {  // prefetch step st+4 before any dependent use
      bb[p] = bp[(size_t)(w * 32 + st + 4) * 64];
#pragma unroll
      for (int tt = 0; tt < 4; ++tt)
        ab[p][tt] = ap[(size_t)((w * 32 + st + 4) * 4 + tt) * 64];
    }

    const bf16x8 bfrag = __builtin_bit_cast(bf16x8, bv);
    acc[0] = __builtin_amdgcn_mfma_f32_16x16x32_bf16(
        __builtin_bit_cast(bf16x8, a0), bfrag, acc[0], 0, 0, 0);
    acc[1] = __builtin_amdgcn_mfma_f32_16x16x32_bf16(
        __builtin_bit_cast(bf16x8, a1), bfrag, acc[1], 0, 0, 0);
    acc[2] = __builtin_amdgcn_mfma_f32_16x16x32_bf16(
        __builtin_bit_cast(bf16x8, a2), bfrag, acc[2], 0, 0, 0);
    acc[3] = __builtin_amdgcn_mfma_f32_16x16x32_bf16(
        __builtin_bit_cast(bf16x8, a3), bfrag, acc[3], 0, 0, 0);
  }

  // ---- cross-wave K reduction + scale + store ----
  __syncthreads();
#pragma unroll
  for (int tt = 0; tt < 4; ++tt) red[w][tt][lane] = acc[tt];
  __syncthreads();
  {
    floatx4 r = red[0][w][lane];
    r += red[1][w][lane];
    r += red[2][w][lane];
    r += red[3][w][lane];
    const float sc = scale[blockIdx.x * 16 + m15];
    r *= sc;
#pragma unroll
    for (int i = 0; i < 4; ++i)
      out[(size_t)(16 * w + q * 4 + i) * N_OUT + blockIdx.x * 16 + m15] = r[i];
  }
}

extern "C" void kernel_launch(void* const* d_in, const int* in_sizes, int n_in,
                              void* d_out, int out_size, void* d_ws, size_t ws_size,
                              hipStream_t stream) {
  const float* x   = (const float*)d_in[0];
  const int*   gi  = (const int*)d_in[1];
  const float* lut = (const float*)d_in[2];
  const float* sc  = (const float*)d_in[3];
  float*       out = (float*)d_out;

  // ws layout: [0, 512 KB) packed-A bf16 ; [1 MB, 1 MB + 90.2 MB) tiled W bf16
  uint32_t* xp = (uint32_t*)d_ws;
  uint4*    wt = (uint4*)((uint8_t*)d_ws + (1u << 20));

  xpack_kernel<<<(N_TOK * K_DIM / 8) / 256, 256, 0, stream>>>(x, xp);
  dequant_kernel<<<(N_OUT * K_DIM / 8) / 256, 256, 0, stream>>>(gi, lut, wt);
  gemm_kernel<<<N_OUT / 16, 256, 0, stream>>>(wt, xp, sc, out);
}